// Round 9
// baseline (386.695 us; speedup 1.0000x reference)
//
#include <hip/hip_runtime.h>
#include <hip/hip_bf16.h>

// CavAttention: B=2, L=5, H=100, W=176, C=256, HEADS=8, DH=32, inner=256
#define LQ 5
#define HWQ 17600
#define NT 35200
#define TPB 8
#define ROWS 40
#define NBLK 4400
#define SCALE_QK 0.17677669529663687f

// LDS (bytes):
//  AO   [40][512] bf16 swzA         : 0 .. 20480   (x-tile; later overwritten by O)
//  per wave w (stride 10368) @ 20480 + w*10368:
//    QKP [40][144]  (q bytes 0-63, k 64-127 | later P k0-63 at 0-128)
//    VT  [32][144]  @ +5760          (V^T: feat rows, spatial cols)
//  gofs [48] i32                     : 61952
//  maskb[48] f32                     : 62144
#define AO_OFF 0
#define WAVE_OFF 20480
#define WAVE_STRIDE 10368
#define VT_OFF 5760
#define GOFS_OFF 61952
#define MASK_OFF 62144
#define SMEM_BYTES 62336

typedef __attribute__((ext_vector_type(8))) short bf16x8;
typedef __attribute__((ext_vector_type(4))) float f32x4;

__device__ __forceinline__ unsigned short f2bf(float f) {
  __hip_bfloat16 b = __float2bfloat16(f);
  return *(unsigned short*)&b;
}
__device__ __forceinline__ unsigned pack2(float a, float b) {
  return ((unsigned)f2bf(b) << 16) | (unsigned)f2bf(a);
}
// AO swizzle (proven rounds 2-7)
__device__ __forceinline__ int swzA(int row, int b) { return (row * 512 + b) ^ ((row & 7) << 4); }
// stride-144 buffers: XOR in-row offset bits 4-5 with row&3 (bijective; 8B/16B aligned preserved)
__device__ __forceinline__ int swzR(int row, int off) { return row * 144 + (off ^ ((row & 3) << 4)); }

// ---- prologue: W_qkv (256x768) -> WqkvT (768x256) bf16; W_out -> WoutT bf16
__global__ void prep_weights(const float* __restrict__ Wqkv,
                             const float* __restrict__ Wout,
                             unsigned short* __restrict__ WqkvT,
                             unsigned short* __restrict__ WoutT) {
  int idx = blockIdx.x * 256 + threadIdx.x;
  if (idx < 256 * 768) {
    int k = idx / 768, n = idx - k * 768;
    WqkvT[n * 256 + k] = f2bf(Wqkv[idx]);
  }
  if (idx < 256 * 256) {
    int k = idx >> 8, n = idx & 255;
    WoutT[n * 256 + k] = f2bf(Wout[idx]);
  }
}

// one head: GEMM1 (qk swapped + v normal) -> QK/VT staged b64 -> scores MFMA ->
// in-reg softmax -> P to LDS -> PV MFMA -> O kept in oacc[6] registers
__device__ __forceinline__ void do_head(int head, const char* AO, char* qkp, char* vt,
                                        const unsigned short* __restrict__ WqkvT,
                                        const f32x4* mrg /*[3] mask bias*/,
                                        int lr, int lg, int lane,
                                        f32x4* oacc /*[6] = [gq*2+nf]*/) {
  const int hb = head * 32;
  const unsigned short* bp[6];
  bp[0] = WqkvT + (hb + lr) * 256 + lg * 8;          // q0
  bp[1] = WqkvT + (hb + 16 + lr) * 256 + lg * 8;     // q1
  bp[2] = WqkvT + (256 + hb + lr) * 256 + lg * 8;    // k0
  bp[3] = WqkvT + (256 + hb + 16 + lr) * 256 + lg * 8;
  bp[4] = WqkvT + (512 + hb + lr) * 256 + lg * 8;    // v0
  bp[5] = WqkvT + (512 + hb + 16 + lr) * 256 + lg * 8;

  f32x4 aqk[4][3], av[2][3];
  #pragma unroll
  for (int j = 0; j < 4; ++j)
    #pragma unroll
    for (int g = 0; g < 3; ++g) aqk[j][g] = (f32x4){0.f, 0.f, 0.f, 0.f};
  #pragma unroll
  for (int j = 0; j < 2; ++j)
    #pragma unroll
    for (int g = 0; g < 3; ++g) av[j][g] = (f32x4){0.f, 0.f, 0.f, 0.f};

  bf16x8 bb0[6], bb1[6];
  #pragma unroll
  for (int j = 0; j < 6; ++j) {
    bb0[j] = *(const bf16x8*)(bp[j]);
    bb1[j] = *(const bf16x8*)(bp[j] + 32);
  }

  #pragma unroll
  for (int kt = 0; kt < 8; ++kt) {
    bf16x8 xf0 = *(const bf16x8*)(AO + swzA(lr,      kt * 64 + lg * 16));
    bf16x8 xf1 = *(const bf16x8*)(AO + swzA(16 + lr, kt * 64 + lg * 16));
    bf16x8 xf2 = *(const bf16x8*)(AO + swzA(32 + lr, kt * 64 + lg * 16)); // rows 40-47 garbage, discarded
    #pragma unroll
    for (int j = 0; j < 4; ++j) {          // q,k swapped: D col = spatial
      bf16x8 w = (kt & 1) ? bb1[j] : bb0[j];
      aqk[j][0] = __builtin_amdgcn_mfma_f32_16x16x32_bf16(w, xf0, aqk[j][0], 0, 0, 0);
      aqk[j][1] = __builtin_amdgcn_mfma_f32_16x16x32_bf16(w, xf1, aqk[j][1], 0, 0, 0);
      aqk[j][2] = __builtin_amdgcn_mfma_f32_16x16x32_bf16(w, xf2, aqk[j][2], 0, 0, 0);
    }
    #pragma unroll
    for (int j = 0; j < 2; ++j) {          // v normal: D col = feat
      bf16x8 w = (kt & 1) ? bb1[4 + j] : bb0[4 + j];
      av[j][0] = __builtin_amdgcn_mfma_f32_16x16x32_bf16(xf0, w, av[j][0], 0, 0, 0);
      av[j][1] = __builtin_amdgcn_mfma_f32_16x16x32_bf16(xf1, w, av[j][1], 0, 0, 0);
      av[j][2] = __builtin_amdgcn_mfma_f32_16x16x32_bf16(xf2, w, av[j][2], 0, 0, 0);
    }
    if (kt < 6) {
      #pragma unroll
      for (int j = 0; j < 6; ++j) {
        bf16x8 nl = *(const bf16x8*)(bp[j] + (kt + 2) * 32);
        if (kt & 1) bb1[j] = nl; else bb0[j] = nl;
      }
    }
  }

  // stage q,k: lane holds (spatial = g*16+lr, feats = (j&1)*16 + lg*4 + 0..3)
  #pragma unroll
  for (int j = 0; j < 4; ++j)
    #pragma unroll
    for (int g = 0; g < 3; ++g) {
      int sp = g * 16 + lr;
      if (sp < ROWS) {
        uint2 w;
        w.x = pack2(aqk[j][g][0], aqk[j][g][1]);
        w.y = pack2(aqk[j][g][2], aqk[j][g][3]);
        int off = (j & 1) * 32 + lg * 8 + ((j >= 2) ? 64 : 0);
        *(uint2*)(qkp + swzR(sp, off)) = w;
      }
    }
  // stage v^T: lane holds (feat = j*16+lr, spatials = g*16 + lg*4 + 0..3)
  #pragma unroll
  for (int j = 0; j < 2; ++j)
    #pragma unroll
    for (int g = 0; g < 3; ++g) {
      if (g < 2 || lg < 2) {               // spatials < 40
        uint2 w;
        w.x = pack2(av[j][g][0], av[j][g][1]);
        w.y = pack2(av[j][g][2], av[j][g][3]);
        *(uint2*)(vt + swzR(j * 16 + lr, g * 32 + lg * 8)) = w;
      }
    }

  // ---- scores = K . Q^T via MFMA: D col = q-spatial, row = k-spatial
  bf16x8 kf0 = *(const bf16x8*)(qkp + swzR(lr,      64 + lg * 16));
  bf16x8 kf1 = *(const bf16x8*)(qkp + swzR(16 + lr, 64 + lg * 16));
  bf16x8 kf2 = *(const bf16x8*)(qkp + swzR(32 + lr, 64 + lg * 16)); // rows 40-47 garbage (masked)
  f32x4 sa[3][3];
  #pragma unroll
  for (int gq = 0; gq < 3; ++gq) {
    bf16x8 qf = *(const bf16x8*)(qkp + swzR(gq * 16 + lr, lg * 16));
    sa[gq][0] = __builtin_amdgcn_mfma_f32_16x16x32_bf16(kf0, qf, (f32x4){0.f,0.f,0.f,0.f}, 0, 0, 0);
    sa[gq][1] = __builtin_amdgcn_mfma_f32_16x16x32_bf16(kf1, qf, (f32x4){0.f,0.f,0.f,0.f}, 0, 0, 0);
    sa[gq][2] = __builtin_amdgcn_mfma_f32_16x16x32_bf16(kf2, qf, (f32x4){0.f,0.f,0.f,0.f}, 0, 0, 0);
  }

  // zero P pad k=48..63 (after the Q/K fragment reads above)
  if (lane < ROWS) {
    *(uint4*)(qkp + swzR(lane, 96))  = make_uint4(0, 0, 0, 0);
    *(uint4*)(qkp + swzR(lane, 112)) = make_uint4(0, 0, 0, 0);
  }

  // ---- softmax per gq: lane holds q = gq*16+lr, k = gk*16+lg*4+reg
  #pragma unroll
  for (int gq = 0; gq < 3; ++gq) {
    int q = gq * 16 + lr;
    int t5 = (q / 5) * 5;
    float v[3][4];
    #pragma unroll
    for (int gk = 0; gk < 3; ++gk)
      #pragma unroll
      for (int r = 0; r < 4; ++r) {
        int k = gk * 16 + lg * 4 + r;
        float raw = sa[gq][gk][r] * SCALE_QK + mrg[gk][r];
        v[gk][r] = ((unsigned)(k - t5) < 5u) ? raw : -1e30f;
      }
    float m = v[0][0];
    #pragma unroll
    for (int gk = 0; gk < 3; ++gk)
      #pragma unroll
      for (int r = 0; r < 4; ++r) m = fmaxf(m, v[gk][r]);
    m = fmaxf(m, __shfl_xor(m, 16));
    m = fmaxf(m, __shfl_xor(m, 32));
    float e[3][4], s = 0.f;
    #pragma unroll
    for (int gk = 0; gk < 3; ++gk)
      #pragma unroll
      for (int r = 0; r < 4; ++r) { e[gk][r] = __expf(v[gk][r] - m); s += e[gk][r]; }
    s += __shfl_xor(s, 16);
    s += __shfl_xor(s, 32);
    float inv = 1.0f / s;
    if (q < ROWS) {
      #pragma unroll
      for (int gk = 0; gk < 3; ++gk) {
        uint2 w;
        w.x = pack2(e[gk][0] * inv, e[gk][1] * inv);
        w.y = pack2(e[gk][2] * inv, e[gk][3] * inv);
        *(uint2*)(qkp + swzR(q, gk * 32 + lg * 8)) = w;   // P[q][k], k = gk*16+lg*4
      }
    }
  }

  // ---- PV via MFMA: O[q][feat] += P[q][k] * V^T[feat][k]
  #pragma unroll
  for (int kt = 0; kt < 2; ++kt) {
    bf16x8 vf0 = *(const bf16x8*)(vt + swzR(lr,      kt * 64 + lg * 16));
    bf16x8 vf1 = *(const bf16x8*)(vt + swzR(16 + lr, kt * 64 + lg * 16));
    #pragma unroll
    for (int gq = 0; gq < 3; ++gq) {
      bf16x8 pf = *(const bf16x8*)(qkp + swzR(gq * 16 + lr, kt * 64 + lg * 16));
      oacc[gq * 2 + 0] = __builtin_amdgcn_mfma_f32_16x16x32_bf16(pf, vf0, oacc[gq * 2 + 0], 0, 0, 0);
      oacc[gq * 2 + 1] = __builtin_amdgcn_mfma_f32_16x16x32_bf16(pf, vf1, oacc[gq * 2 + 1], 0, 0, 0);
    }
  }
}

__global__ __launch_bounds__(256, 2)
void cav_attn_fused(const float* __restrict__ x,
                    const float* __restrict__ mask,
                    const unsigned short* __restrict__ WqkvT,
                    const unsigned short* __restrict__ WoutT,
                    const float* __restrict__ b_out,
                    float* __restrict__ out) {
  extern __shared__ char smem[];
  char*  AO    = smem + AO_OFF;
  int*   gofs  = (int*)(smem + GOFS_OFF);
  float* maskb = (float*)(smem + MASK_OFF);

  const int tid  = threadIdx.x;
  const int wave = tid >> 6;
  const int lane = tid & 63;
  const int lr   = lane & 15;
  const int lg   = lane >> 4;
  const int tile0 = blockIdx.x * TPB;

  // per-row tables; every wave writes identical values -> same-wave reads, no barrier
  if (lane < 48) {
    if (lane < ROWS) {
      int tt = lane / LQ;
      int l  = lane - tt * LQ;
      int gt = tile0 + tt;
      int b  = (gt >= HWQ) ? 1 : 0;
      int rem = gt - b * HWQ;
      gofs[lane]  = (((b * LQ + l) * 100) * 176 + rem) << 8;
      float mv = mask[tile0 * LQ + lane];
      maskb[lane] = (mv == 0.0f) ? -1e30f : 0.0f;
    } else {
      gofs[lane] = 0;
      maskb[lane] = 0.0f;
    }
  }

  char* qkp = smem + WAVE_OFF + wave * WAVE_STRIDE;
  char* vt  = qkp + VT_OFF;

  // FIX (r8 NaN): zero VT spatial cols 40..63 (logical bytes 80..127 per feat row).
  // They are never staged, but PV reduces over k=0..63; P=0 there, and
  // 0 * LDS-garbage(NaN) = NaN. Zeroed once: heads only rewrite bytes 0..79.
  if (lane < 32) {
    *(uint4*)(vt + swzR(lane, 80))  = make_uint4(0, 0, 0, 0);
    *(uint4*)(vt + swzR(lane, 96))  = make_uint4(0, 0, 0, 0);
    *(uint4*)(vt + swzR(lane, 112)) = make_uint4(0, 0, 0, 0);
  }

  // mask bias fragments: mrg[gk][r] = maskb[gk*16 + lg*4 + r]
  f32x4 mrg[3];
  #pragma unroll
  for (int gk = 0; gk < 3; ++gk)
    mrg[gk] = *(const f32x4*)(maskb + gk * 16 + lg * 4);

  // ---- P0: stage x tile -> AO (bf16, swzA)
  #pragma unroll
  for (int i = 0; i < 10; ++i) {
    int r = i * 4 + wave;
    f32x4 v = *(const f32x4*)(x + gofs[r] + lane * 4);
    ushort4 pk;
    pk.x = f2bf(v[0]); pk.y = f2bf(v[1]); pk.z = f2bf(v[2]); pk.w = f2bf(v[3]);
    *(ushort4*)(AO + swzA(r, lane * 8)) = pk;
  }
  __syncthreads();

  f32x4 oacc0[6], oacc1[6];
  #pragma unroll
  for (int i = 0; i < 6; ++i) { oacc0[i] = (f32x4){0.f,0.f,0.f,0.f}; oacc1[i] = (f32x4){0.f,0.f,0.f,0.f}; }

  do_head(wave * 2,     AO, qkp, vt, WqkvT, mrg, lr, lg, lane, oacc0);
  do_head(wave * 2 + 1, AO, qkp, vt, WqkvT, mrg, lr, lg, lane, oacc1);

  __syncthreads();   // all GEMM1 AO-reads done across waves

  // ---- O overwrites AO: lane holds (feat = nf*16+lr, spatials = gq*16+lg*4+rg)
  #pragma unroll
  for (int gq = 0; gq < 3; ++gq)
    #pragma unroll
    for (int nf = 0; nf < 2; ++nf)
      #pragma unroll
      for (int rg = 0; rg < 4; ++rg) {
        int sp = gq * 16 + lg * 4 + rg;
        if (sp < ROWS) {
          int fb0 = (wave * 64 + nf * 16 + lr) * 2;
          *(unsigned short*)(AO + swzA(sp, fb0))      = f2bf(oacc0[gq * 2 + nf][rg]);
          *(unsigned short*)(AO + swzA(sp, fb0 + 64)) = f2bf(oacc1[gq * 2 + nf][rg]);
        }
      }
  __syncthreads();

  // ---- P2 (swapped): out^T tiles = WoutT-frag x O-frag; D col = spatial, row = out-feat
  f32x4 acc2[4][3];
  #pragma unroll
  for (int j = 0; j < 4; ++j)
    #pragma unroll
    for (int g = 0; g < 3; ++g) acc2[j][g] = (f32x4){0.f, 0.f, 0.f, 0.f};

  const unsigned short* bp2[4];
  #pragma unroll
  for (int j = 0; j < 4; ++j)
    bp2[j] = WoutT + (wave * 64 + j * 16 + lr) * 256 + lg * 8;

  bf16x8 cc0[4], cc1[4];
  #pragma unroll
  for (int j = 0; j < 4; ++j) {
    cc0[j] = *(const bf16x8*)(bp2[j]);
    cc1[j] = *(const bf16x8*)(bp2[j] + 32);
  }

  #pragma unroll
  for (int kt = 0; kt < 8; ++kt) {
    bf16x8 of0 = *(const bf16x8*)(AO + swzA(lr,      kt * 64 + lg * 16));
    bf16x8 of1 = *(const bf16x8*)(AO + swzA(16 + lr, kt * 64 + lg * 16));
    bf16x8 of2 = *(const bf16x8*)(AO + swzA(32 + lr, kt * 64 + lg * 16));
    #pragma unroll
    for (int j = 0; j < 4; ++j) {
      bf16x8 w = (kt & 1) ? cc1[j] : cc0[j];
      acc2[j][0] = __builtin_amdgcn_mfma_f32_16x16x32_bf16(w, of0, acc2[j][0], 0, 0, 0);
      acc2[j][1] = __builtin_amdgcn_mfma_f32_16x16x32_bf16(w, of1, acc2[j][1], 0, 0, 0);
      acc2[j][2] = __builtin_amdgcn_mfma_f32_16x16x32_bf16(w, of2, acc2[j][2], 0, 0, 0);
    }
    if (kt < 6) {
      #pragma unroll
      for (int j = 0; j < 4; ++j) {
        bf16x8 nl = *(const bf16x8*)(bp2[j] + (kt + 2) * 32);
        if (kt & 1) cc1[j] = nl; else cc0[j] = nl;
      }
    }
  }

  // ---- stores: lane holds (spatial = g*16+lr, outfeats = wave*64 + j*16 + lg*4 + 0..3)
  f32x4 bias[4];
  #pragma unroll
  for (int j = 0; j < 4; ++j)
    bias[j] = *(const f32x4*)(b_out + wave * 64 + j * 16 + lg * 4);

  #pragma unroll
  for (int g = 0; g < 3; ++g) {
    int sp = g * 16 + lr;
    if (sp < ROWS) {
      int go = gofs[sp];
      #pragma unroll
      for (int j = 0; j < 4; ++j) {
        f32x4 v = acc2[j][g] + bias[j];
        *(f32x4*)(out + go + wave * 64 + j * 16 + lg * 4) = v;
      }
    }
  }
}

extern "C" void kernel_launch(void* const* d_in, const int* in_sizes, int n_in,
                              void* d_out, int out_size, void* d_ws, size_t ws_size,
                              hipStream_t stream) {
  (void)in_sizes; (void)n_in; (void)out_size; (void)ws_size;
  const float* x    = (const float*)d_in[0];
  const float* mask = (const float*)d_in[1];
  const float* Wqkv = (const float*)d_in[2];
  const float* Wout = (const float*)d_in[3];
  const float* bout = (const float*)d_in[4];
  float* out = (float*)d_out;

  unsigned short* WqkvT = (unsigned short*)d_ws;        // [768][256]
  unsigned short* WoutT = WqkvT + 768 * 256;            // [256][256]

  prep_weights<<<768, 256, 0, stream>>>(Wqkv, Wout, WqkvT, WoutT);
  cav_attn_fused<<<NBLK, 256, SMEM_BYTES, stream>>>(x, mask, WqkvT, WoutT, bout, out);
}

// Round 10
// 379.187 us; speedup vs baseline: 1.0198x; 1.0198x over previous
//
#include <hip/hip_runtime.h>
#include <hip/hip_bf16.h>

// CavAttention: B=2, L=5, H=100, W=176, C=256, HEADS=8, DH=32, inner=256
#define LQ 5
#define HWQ 17600
#define NT 35200
#define TPB 8
#define ROWS 40
#define NBLK 4400
#define SCALE_QK 0.17677669529663687f

// LDS (bytes):
//  AO   [40][512] bf16 swzA   : 0 .. 20480  (x-tile; later overwritten by O)
//  qkp  4w x [48][128] swz128 : 20480 + w*6144 .. 45056
//       (q bytes 0-63, k 64-127; P later overwrites 0-127; rows 40-47 zeroed pad)
//  gofs [48] i32              : 45056
//  maskb[48] f32              : 45248
#define AO_OFF 0
#define QKP_OFF 20480
#define QKP_STRIDE 6144
#define GOFS_OFF 45056
#define MASK_OFF 45248
#define SMEM_BYTES 45440

typedef __attribute__((ext_vector_type(8))) short bf16x8;
typedef __attribute__((ext_vector_type(4))) float f32x4;

__device__ __forceinline__ unsigned short f2bf(float f) {
  __hip_bfloat16 b = __float2bfloat16(f);
  return *(unsigned short*)&b;
}
__device__ __forceinline__ unsigned pack2(float a, float b) {
  return ((unsigned)f2bf(b) << 16) | (unsigned)f2bf(a);
}
// AO swizzle (proven rounds 2-9)
__device__ __forceinline__ int swzA(int row, int b) { return (row * 512 + b) ^ ((row & 7) << 4); }
// 128B-stride buffer: XOR in-row bits 4-6 with row&7 (row term = 32 words == 0 mod 32,
// XOR spreads 16-lane groups across all banks -> 2-way max)
__device__ __forceinline__ int swz128(int row, int off) { return row * 128 + (off ^ ((row & 7) << 4)); }

// ---- prologue: W_qkv (256x768) -> WqkvT (768x256) bf16; W_out -> WoutT bf16
__global__ void prep_weights(const float* __restrict__ Wqkv,
                             const float* __restrict__ Wout,
                             unsigned short* __restrict__ WqkvT,
                             unsigned short* __restrict__ WoutT) {
  int idx = blockIdx.x * 256 + threadIdx.x;
  if (idx < 256 * 768) {
    int k = idx / 768, n = idx - k * 768;
    WqkvT[n * 256 + k] = f2bf(Wqkv[idx]);
  }
  if (idx < 256 * 256) {
    int k = idx >> 8, n = idx & 255;
    WoutT[n * 256 + k] = f2bf(Wout[idx]);
  }
}

// one head: GEMM1 (qk swapped + v normal) -> q,k staged b64 -> scores MFMA ->
// in-reg softmax -> P to LDS -> PV MFMA with V^T B-frags built via ds_bpermute
__device__ __forceinline__ void do_head(int head, const char* AO, char* qkp,
                                        const unsigned short* __restrict__ WqkvT,
                                        const f32x4* mrg /*[3] mask bias*/,
                                        int lr, int lg, int lane,
                                        f32x4* oacc /*[6] = [gq*2+nf]*/) {
  const int hb = head * 32;
  const unsigned short* bp[6];
  bp[0] = WqkvT + (hb + lr) * 256 + lg * 8;          // q0
  bp[1] = WqkvT + (hb + 16 + lr) * 256 + lg * 8;     // q1
  bp[2] = WqkvT + (256 + hb + lr) * 256 + lg * 8;    // k0
  bp[3] = WqkvT + (256 + hb + 16 + lr) * 256 + lg * 8;
  bp[4] = WqkvT + (512 + hb + lr) * 256 + lg * 8;    // v0
  bp[5] = WqkvT + (512 + hb + 16 + lr) * 256 + lg * 8;

  f32x4 aqk[4][3], av[2][3];
  #pragma unroll
  for (int j = 0; j < 4; ++j)
    #pragma unroll
    for (int g = 0; g < 3; ++g) aqk[j][g] = (f32x4){0.f, 0.f, 0.f, 0.f};
  #pragma unroll
  for (int j = 0; j < 2; ++j)
    #pragma unroll
    for (int g = 0; g < 3; ++g) av[j][g] = (f32x4){0.f, 0.f, 0.f, 0.f};

  bf16x8 bb0[6], bb1[6];
  #pragma unroll
  for (int j = 0; j < 6; ++j) {
    bb0[j] = *(const bf16x8*)(bp[j]);
    bb1[j] = *(const bf16x8*)(bp[j] + 32);
  }

  #pragma unroll
  for (int kt = 0; kt < 8; ++kt) {
    bf16x8 xf0 = *(const bf16x8*)(AO + swzA(lr,      kt * 64 + lg * 16));
    bf16x8 xf1 = *(const bf16x8*)(AO + swzA(16 + lr, kt * 64 + lg * 16));
    bf16x8 xf2 = *(const bf16x8*)(AO + swzA(32 + lr, kt * 64 + lg * 16)); // rows 40-47 garbage, discarded
    #pragma unroll
    for (int j = 0; j < 4; ++j) {          // q,k swapped: D col = spatial
      bf16x8 w = (kt & 1) ? bb1[j] : bb0[j];
      aqk[j][0] = __builtin_amdgcn_mfma_f32_16x16x32_bf16(w, xf0, aqk[j][0], 0, 0, 0);
      aqk[j][1] = __builtin_amdgcn_mfma_f32_16x16x32_bf16(w, xf1, aqk[j][1], 0, 0, 0);
      aqk[j][2] = __builtin_amdgcn_mfma_f32_16x16x32_bf16(w, xf2, aqk[j][2], 0, 0, 0);
    }
    #pragma unroll
    for (int j = 0; j < 2; ++j) {          // v normal: D col = feat
      bf16x8 w = (kt & 1) ? bb1[4 + j] : bb0[4 + j];
      av[j][0] = __builtin_amdgcn_mfma_f32_16x16x32_bf16(xf0, w, av[j][0], 0, 0, 0);
      av[j][1] = __builtin_amdgcn_mfma_f32_16x16x32_bf16(xf1, w, av[j][1], 0, 0, 0);
      av[j][2] = __builtin_amdgcn_mfma_f32_16x16x32_bf16(xf2, w, av[j][2], 0, 0, 0);
    }
    if (kt < 6) {
      #pragma unroll
      for (int j = 0; j < 6; ++j) {
        bf16x8 nl = *(const bf16x8*)(bp[j] + (kt + 2) * 32);
        if (kt & 1) bb1[j] = nl; else bb0[j] = nl;
      }
    }
  }

  // stage q,k: lane holds (spatial = g*16+lr, feats = (j&1)*16 + lg*4 + 0..3)
  #pragma unroll
  for (int j = 0; j < 4; ++j)
    #pragma unroll
    for (int g = 0; g < 3; ++g) {
      int sp = g * 16 + lr;
      if (sp < ROWS) {
        uint2 w;
        w.x = pack2(aqk[j][g][0], aqk[j][g][1]);
        w.y = pack2(aqk[j][g][2], aqk[j][g][3]);
        int off = (j & 1) * 32 + lg * 8 + ((j >= 2) ? 64 : 0);
        *(uint2*)(qkp + swz128(sp, off)) = w;
      }
    }

  // pack v D-frags for cross-lane B-frag construction (lane: feat=j*16+lr,
  // spatials g*16+lg*4+0..3). g=2 holds spatials 40-47 in lanes lg>=2 -> zero.
  const bool lgHi = (lane >= 32);
  unsigned pv[2][3][2];
  #pragma unroll
  for (int j = 0; j < 2; ++j)
    #pragma unroll
    for (int g = 0; g < 3; ++g) {
      unsigned w0 = pack2(av[j][g][0], av[j][g][1]);
      unsigned w1 = pack2(av[j][g][2], av[j][g][3]);
      if (g == 2 && lgHi) { w0 = 0; w1 = 0; }
      pv[j][g][0] = w0; pv[j][g][1] = w1;
    }

  // ---- scores = K . Q^T via MFMA: D col = q-spatial, row = k-spatial
  bf16x8 kf0 = *(const bf16x8*)(qkp + swz128(lr,      64 + lg * 16));
  bf16x8 kf1 = *(const bf16x8*)(qkp + swz128(16 + lr, 64 + lg * 16));
  bf16x8 kf2 = *(const bf16x8*)(qkp + swz128(32 + lr, 64 + lg * 16)); // rows 40-47 zeroed pad
  f32x4 sa[3][3];
  #pragma unroll
  for (int gq = 0; gq < 3; ++gq) {
    bf16x8 qf = *(const bf16x8*)(qkp + swz128(gq * 16 + lr, lg * 16));
    sa[gq][0] = __builtin_amdgcn_mfma_f32_16x16x32_bf16(kf0, qf, (f32x4){0.f,0.f,0.f,0.f}, 0, 0, 0);
    sa[gq][1] = __builtin_amdgcn_mfma_f32_16x16x32_bf16(kf1, qf, (f32x4){0.f,0.f,0.f,0.f}, 0, 0, 0);
    sa[gq][2] = __builtin_amdgcn_mfma_f32_16x16x32_bf16(kf2, qf, (f32x4){0.f,0.f,0.f,0.f}, 0, 0, 0);
  }

  // ---- softmax per gq: lane holds q = gq*16+lr, k = gk*16+lg*4+reg
  #pragma unroll
  for (int gq = 0; gq < 3; ++gq) {
    int q = gq * 16 + lr;
    int t5 = (q / 5) * 5;
    float v[3][4];
    #pragma unroll
    for (int gk = 0; gk < 3; ++gk)
      #pragma unroll
      for (int r = 0; r < 4; ++r) {
        int k = gk * 16 + lg * 4 + r;
        float raw = sa[gq][gk][r] * SCALE_QK + mrg[gk][r];
        v[gk][r] = ((unsigned)(k - t5) < 5u) ? raw : -1e30f;
      }
    float m = v[0][0];
    #pragma unroll
    for (int gk = 0; gk < 3; ++gk)
      #pragma unroll
      for (int r = 0; r < 4; ++r) m = fmaxf(m, v[gk][r]);
    m = fmaxf(m, __shfl_xor(m, 16));
    m = fmaxf(m, __shfl_xor(m, 32));
    float e[3][4], s = 0.f;
    #pragma unroll
    for (int gk = 0; gk < 3; ++gk)
      #pragma unroll
      for (int r = 0; r < 4; ++r) { e[gk][r] = __expf(v[gk][r] - m); s += e[gk][r]; }
    s += __shfl_xor(s, 16);
    s += __shfl_xor(s, 32);
    float inv = 1.0f / s;
    if (q < ROWS) {
      #pragma unroll
      for (int gk = 0; gk < 3; ++gk) {
        uint2 w;
        w.x = pack2(e[gk][0] * inv, e[gk][1] * inv);
        w.y = pack2(e[gk][2] * inv, e[gk][3] * inv);
        *(uint2*)(qkp + swz128(q, gk * 32 + lg * 8)) = w;   // P[q][k-slots gk*16+lg*4..+3]
      }
    }
  }
  // P k-slots 48..63 = stale finite k-bytes; their vf is forced 0 below -> safe.

  // ---- PV via MFMA: O[q][feat] += P[q][k] * V^T[feat][k]; V^T B-frags via bpermute.
  // vf word w (spatials s0+2w..+1, s0=kt*32+lg*8): source lane ((lg&1)*2 + (w>>1))*16+lr,
  // register pv[j][kt*2 + (lg>>1)][w&1]; (kt==1 && lg>=2) -> spatials 48-63 -> 0.
  const int idxA = (((lane & 16) ? 32 : 0) + lr) * 4;
  const int idxB = idxA + 64;
  #pragma unroll
  for (int kt = 0; kt < 2; ++kt) {
    union { unsigned u[4]; bf16x8 v; } vf[2];
    #pragma unroll
    for (int j = 0; j < 2; ++j)
      #pragma unroll
      for (int w = 0; w < 4; ++w) {
        int idx = (w >> 1) ? idxB : idxA;
        unsigned a = (unsigned)__builtin_amdgcn_ds_bpermute(idx, (int)pv[j][2 * kt][w & 1]);
        unsigned b = (kt == 0) ? (unsigned)__builtin_amdgcn_ds_bpermute(idx, (int)pv[j][1][w & 1]) : 0u;
        vf[j].u[w] = lgHi ? b : a;
      }
    #pragma unroll
    for (int gq = 0; gq < 3; ++gq) {
      bf16x8 pf = *(const bf16x8*)(qkp + swz128(gq * 16 + lr, kt * 64 + lg * 16));
      oacc[gq * 2 + 0] = __builtin_amdgcn_mfma_f32_16x16x32_bf16(pf, vf[0].v, oacc[gq * 2 + 0], 0, 0, 0);
      oacc[gq * 2 + 1] = __builtin_amdgcn_mfma_f32_16x16x32_bf16(pf, vf[1].v, oacc[gq * 2 + 1], 0, 0, 0);
    }
  }
}

__global__ __launch_bounds__(256, 2)
void cav_attn_fused(const float* __restrict__ x,
                    const float* __restrict__ mask,
                    const unsigned short* __restrict__ WqkvT,
                    const unsigned short* __restrict__ WoutT,
                    const float* __restrict__ b_out,
                    float* __restrict__ out) {
  extern __shared__ char smem[];
  char*  AO    = smem + AO_OFF;
  int*   gofs  = (int*)(smem + GOFS_OFF);
  float* maskb = (float*)(smem + MASK_OFF);

  const int tid  = threadIdx.x;
  const int wave = tid >> 6;
  const int lane = tid & 63;
  const int lr   = lane & 15;
  const int lg   = lane >> 4;
  const int tile0 = blockIdx.x * TPB;

  // per-row tables; every wave writes identical values -> same-wave reads, no barrier
  if (lane < 48) {
    if (lane < ROWS) {
      int tt = lane / LQ;
      int l  = lane - tt * LQ;
      int gt = tile0 + tt;
      int b  = (gt >= HWQ) ? 1 : 0;
      int rem = gt - b * HWQ;
      gofs[lane]  = (((b * LQ + l) * 100) * 176 + rem) << 8;
      float mv = mask[tile0 * LQ + lane];
      maskb[lane] = (mv == 0.0f) ? -1e30f : 0.0f;
    } else {
      gofs[lane] = 0;
      maskb[lane] = 0.0f;
    }
  }

  char* qkp = smem + QKP_OFF + wave * QKP_STRIDE;
  // zero qkp pad rows 40-47 once (read as kf/pf tile pad; heads never write them)
  {
    int zr = 40 + (lane >> 3);
    int zb = (lane & 7) * 16;
    *(uint4*)(qkp + swz128(zr, zb)) = make_uint4(0, 0, 0, 0);
  }

  // mask bias fragments: mrg[gk][r] = maskb[gk*16 + lg*4 + r]
  f32x4 mrg[3];
  #pragma unroll
  for (int gk = 0; gk < 3; ++gk)
    mrg[gk] = *(const f32x4*)(maskb + gk * 16 + lg * 4);

  // ---- P0: stage x tile -> AO (bf16, swzA)
  #pragma unroll
  for (int i = 0; i < 10; ++i) {
    int r = i * 4 + wave;
    f32x4 v = *(const f32x4*)(x + gofs[r] + lane * 4);
    ushort4 pk;
    pk.x = f2bf(v[0]); pk.y = f2bf(v[1]); pk.z = f2bf(v[2]); pk.w = f2bf(v[3]);
    *(ushort4*)(AO + swzA(r, lane * 8)) = pk;
  }
  __syncthreads();

  f32x4 oacc0[6], oacc1[6];
  #pragma unroll
  for (int i = 0; i < 6; ++i) { oacc0[i] = (f32x4){0.f,0.f,0.f,0.f}; oacc1[i] = (f32x4){0.f,0.f,0.f,0.f}; }

  do_head(wave * 2,     AO, qkp, WqkvT, mrg, lr, lg, lane, oacc0);
  do_head(wave * 2 + 1, AO, qkp, WqkvT, mrg, lr, lg, lane, oacc1);

  __syncthreads();   // all GEMM1 AO-reads done across waves

  // ---- O overwrites AO: lane holds (feat = nf*16+lr, spatials = gq*16+lg*4+rg)
  #pragma unroll
  for (int gq = 0; gq < 3; ++gq)
    #pragma unroll
    for (int nf = 0; nf < 2; ++nf)
      #pragma unroll
      for (int rg = 0; rg < 4; ++rg) {
        int sp = gq * 16 + lg * 4 + rg;
        if (sp < ROWS) {
          int fb0 = (wave * 64 + nf * 16 + lr) * 2;
          *(unsigned short*)(AO + swzA(sp, fb0))      = f2bf(oacc0[gq * 2 + nf][rg]);
          *(unsigned short*)(AO + swzA(sp, fb0 + 64)) = f2bf(oacc1[gq * 2 + nf][rg]);
        }
      }
  __syncthreads();

  // ---- P2 (swapped): D col = spatial, row = out-feat
  f32x4 acc2[4][3];
  #pragma unroll
  for (int j = 0; j < 4; ++j)
    #pragma unroll
    for (int g = 0; g < 3; ++g) acc2[j][g] = (f32x4){0.f, 0.f, 0.f, 0.f};

  const unsigned short* bp2[4];
  #pragma unroll
  for (int j = 0; j < 4; ++j)
    bp2[j] = WoutT + (wave * 64 + j * 16 + lr) * 256 + lg * 8;

  bf16x8 cc0[4], cc1[4];
  #pragma unroll
  for (int j = 0; j < 4; ++j) {
    cc0[j] = *(const bf16x8*)(bp2[j]);
    cc1[j] = *(const bf16x8*)(bp2[j] + 32);
  }

  #pragma unroll
  for (int kt = 0; kt < 8; ++kt) {
    bf16x8 of0 = *(const bf16x8*)(AO + swzA(lr,      kt * 64 + lg * 16));
    bf16x8 of1 = *(const bf16x8*)(AO + swzA(16 + lr, kt * 64 + lg * 16));
    bf16x8 of2 = *(const bf16x8*)(AO + swzA(32 + lr, kt * 64 + lg * 16));
    #pragma unroll
    for (int j = 0; j < 4; ++j) {
      bf16x8 w = (kt & 1) ? cc1[j] : cc0[j];
      acc2[j][0] = __builtin_amdgcn_mfma_f32_16x16x32_bf16(w, of0, acc2[j][0], 0, 0, 0);
      acc2[j][1] = __builtin_amdgcn_mfma_f32_16x16x32_bf16(w, of1, acc2[j][1], 0, 0, 0);
      acc2[j][2] = __builtin_amdgcn_mfma_f32_16x16x32_bf16(w, of2, acc2[j][2], 0, 0, 0);
    }
    if (kt < 6) {
      #pragma unroll
      for (int j = 0; j < 4; ++j) {
        bf16x8 nl = *(const bf16x8*)(bp2[j] + (kt + 2) * 32);
        if (kt & 1) cc1[j] = nl; else cc0[j] = nl;
      }
    }
  }

  // ---- stores: lane holds (spatial = g*16+lr, outfeats = wave*64 + j*16 + lg*4 + 0..3)
  f32x4 bias[4];
  #pragma unroll
  for (int j = 0; j < 4; ++j)
    bias[j] = *(const f32x4*)(b_out + wave * 64 + j * 16 + lg * 4);

  #pragma unroll
  for (int g = 0; g < 3; ++g) {
    int sp = g * 16 + lr;
    if (sp < ROWS) {
      int go = gofs[sp];
      #pragma unroll
      for (int j = 0; j < 4; ++j) {
        f32x4 v = acc2[j][g] + bias[j];
        *(f32x4*)(out + go + wave * 64 + j * 16 + lg * 4) = v;
      }
    }
  }
}

extern "C" void kernel_launch(void* const* d_in, const int* in_sizes, int n_in,
                              void* d_out, int out_size, void* d_ws, size_t ws_size,
                              hipStream_t stream) {
  (void)in_sizes; (void)n_in; (void)out_size; (void)ws_size;
  const float* x    = (const float*)d_in[0];
  const float* mask = (const float*)d_in[1];
  const float* Wqkv = (const float*)d_in[2];
  const float* Wout = (const float*)d_in[3];
  const float* bout = (const float*)d_in[4];
  float* out = (float*)d_out;

  unsigned short* WqkvT = (unsigned short*)d_ws;        // [768][256]
  unsigned short* WoutT = WqkvT + 768 * 256;            // [256][256]

  prep_weights<<<768, 256, 0, stream>>>(Wqkv, Wout, WqkvT, WoutT);
  cav_attn_fused<<<NBLK, 256, SMEM_BYTES, stream>>>(x, mask, WqkvT, WoutT, bout, out);
}